// Round 1
// 191.116 us; speedup vs baseline: 1.0323x; 1.0323x over previous
//
#include <hip/hip_runtime.h>
#include <math.h>

// Problem constants: 20 qubits, B=16 batch, RX chain on qubit 0,
// 2-qubit Hamiltonian evolution on qubits (2,5), observable = sum_q Z_q.
// State layout: (dim, B) row-major => flat idx = i*B + b; qubit q bit of i is at
// bit position (19 - q). So qubit 0 -> bit 19, qubit 2 -> bit 17, qubit 5 -> bit 14.
constexpr int NQ     = 20;
constexpr int DIM    = 1 << NQ;
constexpr int B      = 16;
constexpr int GROUPS = 1 << 17;   // DIM / 8 (octets over bits 19,17,14)
constexpr int NBLK   = 1024;
constexpr int NTHR   = 512;       // 1024*512 = 2^19 threads = GROUPS * 4 batch-quads

// ws layout (floats):
//   [0..15]    cos(0.5*sum theta) per batch
//   [16..31]   sin(0.5*sum theta) per batch
//   [32..543]  Ue per batch: b*32 + (i*4+j)*2 (+1 imag)
//   [544..]    per-block partials: NBLK*16 floats

// ---- Prep: composed RX coefficients + exp(-i t H) via fp64 scaling-squaring ----
__global__ void prep_kernel(const float* __restrict__ hre, const float* __restrict__ him,
                            const float* __restrict__ theta, const float* __restrict__ tv,
                            float* __restrict__ ws) {
  int b = threadIdx.x;
  if (b >= B) return;

  // All RX on the same qubit commute: product = RX(sum theta).
  double th = 0.0;
  for (int k = 0; k < 8; k++) th += (double)theta[k * B + b];
  th *= 0.5;
  ws[b]     = (float)cos(th);
  ws[B + b] = (float)sin(th);

  // H = 0.5*(A + A^H);  M = -i * t * H  =>  Mre = t*Him, Mim = -t*Hre
  double t = (double)tv[b];
  double Mre[4][4], Mim[4][4];
  for (int i = 0; i < 4; i++)
    for (int j = 0; j < 4; j++) {
      double are = hre[(i*4+j)*B + b], aim = him[(i*4+j)*B + b];
      double cre = hre[(j*4+i)*B + b], cim = him[(j*4+i)*B + b];
      double Hre = 0.5*(are + cre), Him = 0.5*(aim - cim);
      Mre[i][j] = t * Him;
      Mim[i][j] = -t * Hre;
    }

  // Scaling: inf-norm upper bound, halve until <= 0.25
  double ninf = 0.0;
  for (int i = 0; i < 4; i++) {
    double r = 0.0;
    for (int j = 0; j < 4; j++) r += fabs(Mre[i][j]) + fabs(Mim[i][j]);
    ninf = fmax(ninf, r);
  }
  int sc = 0;
  while (ninf > 0.25 && sc < 40) { ninf *= 0.5; sc++; }
  double scale = ldexp(1.0, -sc);
  for (int i = 0; i < 4; i++)
    for (int j = 0; j < 4; j++) { Mre[i][j] *= scale; Mim[i][j] *= scale; }

  // Taylor via Horner: T = I; for k=K..1: T = I + M*T/k
  double Tre[4][4], Tim[4][4];
  for (int i = 0; i < 4; i++)
    for (int j = 0; j < 4; j++) { Tre[i][j] = (i==j) ? 1.0 : 0.0; Tim[i][j] = 0.0; }
  for (int k = 13; k >= 1; k--) {
    double Pre[4][4], Pim[4][4];
    double inv = 1.0 / (double)k;
    for (int i = 0; i < 4; i++)
      for (int j = 0; j < 4; j++) {
        double rr = 0.0, ii = 0.0;
        for (int m = 0; m < 4; m++) {
          rr += Mre[i][m]*Tre[m][j] - Mim[i][m]*Tim[m][j];
          ii += Mre[i][m]*Tim[m][j] + Mim[i][m]*Tre[m][j];
        }
        Pre[i][j] = rr*inv + ((i==j) ? 1.0 : 0.0);
        Pim[i][j] = ii*inv;
      }
    for (int i = 0; i < 4; i++)
      for (int j = 0; j < 4; j++) { Tre[i][j] = Pre[i][j]; Tim[i][j] = Pim[i][j]; }
  }
  // Squaring
  for (int q = 0; q < sc; q++) {
    double Pre[4][4], Pim[4][4];
    for (int i = 0; i < 4; i++)
      for (int j = 0; j < 4; j++) {
        double rr = 0.0, ii = 0.0;
        for (int m = 0; m < 4; m++) {
          rr += Tre[i][m]*Tre[m][j] - Tim[i][m]*Tim[m][j];
          ii += Tre[i][m]*Tim[m][j] + Tim[i][m]*Tre[m][j];
        }
        Pre[i][j] = rr; Pim[i][j] = ii;
      }
    for (int i = 0; i < 4; i++)
      for (int j = 0; j < 4; j++) { Tre[i][j] = Pre[i][j]; Tim[i][j] = Pim[i][j]; }
  }

  float* ue = ws + 2*B + b*32;
  for (int i = 0; i < 4; i++)
    for (int j = 0; j < 4; j++) {
      ue[(i*4+j)*2]     = (float)Tre[i][j];
      ue[(i*4+j)*2 + 1] = (float)Tim[i][j];
    }
}

// RX(theta_sum) on qubit 0, applied per float4 component (component = batch within quad).
#define RXPAIR(j, f) { \
  float xr = R[j].f, xi = I[j].f, yr = R[(j)+4].f, yi = I[(j)+4].f; \
  R[j].f     = fmaf(c4.f, xr,  s4.f * yi); \
  I[j].f     = fmaf(c4.f, xi, -s4.f * yr); \
  R[(j)+4].f = fmaf(s4.f, xi,  c4.f * yr); \
  I[(j)+4].f = fmaf(c4.f, yi, -s4.f * xr); \
}

// Ue on (qubit2, qubit5) + weight-folded |amp|^2 accumulation for one batch (bi-th
// component f of the float4s). U rows read from LDS (broadcast, conflict-free pad).
#define UE_BI(f, bi, accv) \
  float accv = 0.f; \
  { \
    const float* ub = &u_lds[(b0 + (bi)) * 36]; \
    _Pragma("unroll") \
    for (int k = 0; k < 4; k++) { \
      float4 u0 = *(const float4*)(ub + 8*k);       /* ur0,ui0,ur1,ui1 */ \
      float4 u1 = *(const float4*)(ub + 8*k + 4);   /* ur2,ui2,ur3,ui3 */ \
      float rr0 = fmaf(u0.x, R[0].f, -u0.y * I[0].f); \
      rr0 = fmaf(u0.z, R[1].f, rr0); rr0 = fmaf(-u0.w, I[1].f, rr0); \
      rr0 = fmaf(u1.x, R[2].f, rr0); rr0 = fmaf(-u1.y, I[2].f, rr0); \
      rr0 = fmaf(u1.z, R[3].f, rr0); rr0 = fmaf(-u1.w, I[3].f, rr0); \
      float ii0 = fmaf(u0.x, I[0].f, u0.y * R[0].f); \
      ii0 = fmaf(u0.z, I[1].f, ii0); ii0 = fmaf(u0.w, R[1].f, ii0); \
      ii0 = fmaf(u1.x, I[2].f, ii0); ii0 = fmaf(u1.y, R[2].f, ii0); \
      ii0 = fmaf(u1.z, I[3].f, ii0); ii0 = fmaf(u1.w, R[3].f, ii0); \
      float rr1 = fmaf(u0.x, R[4].f, -u0.y * I[4].f); \
      rr1 = fmaf(u0.z, R[5].f, rr1); rr1 = fmaf(-u0.w, I[5].f, rr1); \
      rr1 = fmaf(u1.x, R[6].f, rr1); rr1 = fmaf(-u1.y, I[6].f, rr1); \
      rr1 = fmaf(u1.z, R[7].f, rr1); rr1 = fmaf(-u1.w, I[7].f, rr1); \
      float ii1 = fmaf(u0.x, I[4].f, u0.y * R[4].f); \
      ii1 = fmaf(u0.z, I[5].f, ii1); ii1 = fmaf(u0.w, R[5].f, ii1); \
      ii1 = fmaf(u1.x, I[6].f, ii1); ii1 = fmaf(u1.y, R[6].f, ii1); \
      ii1 = fmaf(u1.z, I[7].f, ii1); ii1 = fmaf(u1.w, R[7].f, ii1); \
      int sb = (k & 1) + (k >> 1); \
      float w0 = wb + (float)(3 - 2*sb);            /* h=0 weight */ \
      accv = fmaf(fmaf(rr0, rr0, ii0*ii0), w0,       accv); \
      accv = fmaf(fmaf(rr1, rr1, ii1*ii1), w0 - 2.f, accv); \
    } \
  }

// ---- Fused gate-apply + expectation. One group x 4 batches per thread; float4 loads. ----
__global__ __launch_bounds__(NTHR) void fused_kernel(
    const float* __restrict__ sre, const float* __restrict__ sim,
    const float* __restrict__ ws, float* __restrict__ partial) {
  __shared__ float u_lds[16 * 36];   // padded stride 36: 16B-aligned rows, conflict-free
  __shared__ float cs_lds[32];
  __shared__ float red[16];

  int t = threadIdx.x;
  {
    int b = t >> 5, e = t & 31;
    u_lds[b * 36 + e] = ws[2 * B + b * 32 + e];
  }
  if (t < 32) cs_lds[t] = ws[t];
  if (t < 16) red[t] = 0.f;
  __syncthreads();

  int tid = blockIdx.x * NTHR + t;
  int g   = tid >> 2;                  // 2^17 groups, exact cover
  int b0  = (tid & 3) << 2;            // batch quad base: 0,4,8,12
  // expand 17-bit group id into 20-bit base with bits 14,17,19 zero
  int base = (g & 0x3FFF) | ((g & 0xC000) << 1) | ((g & 0x10000) << 2);
  const float* pr = sre + base * B + b0;
  const float* pi = sim + base * B + b0;

  float4 R[8], I[8];
  #pragma unroll
  for (int j = 0; j < 8; j++) {
    int off = (((((j >> 2) & 1) << 19) | (((j >> 1) & 1) << 17) | ((j & 1) << 14))) * B;
    R[j] = *(const float4*)(pr + off);
    I[j] = *(const float4*)(pi + off);
  }

  float4 c4 = *(const float4*)&cs_lds[b0];
  float4 s4 = *(const float4*)&cs_lds[16 + b0];

  // RX on qubit 0 (bit j>>2): pairs (j, j+4); -i*s*(x) = s*xi - i*s*xr
  #pragma unroll
  for (int j = 0; j < 4; j++) {
    RXPAIR(j, x) RXPAIR(j, y) RXPAIR(j, z) RXPAIR(j, w)
  }

  int pc = __popc(base);
  float wb = (float)(17 - 2 * pc);

  UE_BI(x, 0, acc0)
  UE_BI(y, 1, acc1)
  UE_BI(z, 2, acc2)
  UE_BI(w, 3, acc3)

  // lanes with equal (t&3) share the batch quad => butterfly over lane bits 2..5
  #pragma unroll
  for (int m = 4; m <= 32; m <<= 1) {
    acc0 += __shfl_xor(acc0, m, 64);
    acc1 += __shfl_xor(acc1, m, 64);
    acc2 += __shfl_xor(acc2, m, 64);
    acc3 += __shfl_xor(acc3, m, 64);
  }

  if ((t & 63) < 4) {
    int bb = (t & 3) << 2;
    atomicAdd(&red[bb + 0], acc0);
    atomicAdd(&red[bb + 1], acc1);
    atomicAdd(&red[bb + 2], acc2);
    atomicAdd(&red[bb + 3], acc3);
  }
  __syncthreads();
  if (t < 16) partial[blockIdx.x * 16 + t] = red[t];
}

// ---- Final reduction over per-block partials ----
__global__ void reduce_kernel(const float* __restrict__ partial, float* __restrict__ out) {
  int t = threadIdx.x;       // 256 threads
  int b = t & 15;
  float acc = 0.f;
  for (int i = t >> 4; i < NBLK; i += 16)
    acc += partial[i * 16 + b];
  acc += __shfl_xor(acc, 16, 64);
  acc += __shfl_xor(acc, 32, 64);
  __shared__ float red[16];
  if (t < 16) red[t] = 0.f;
  __syncthreads();
  if ((t & 63) < 16) atomicAdd(&red[t & 15], acc);
  __syncthreads();
  if (t < 16) out[t] = red[t];
}

extern "C" void kernel_launch(void* const* d_in, const int* in_sizes, int n_in,
                              void* d_out, int out_size, void* d_ws, size_t ws_size,
                              hipStream_t stream) {
  const float* sre = (const float*)d_in[0];
  const float* sim = (const float*)d_in[1];
  const float* hre = (const float*)d_in[2];
  const float* him = (const float*)d_in[3];
  const float* th  = (const float*)d_in[4];
  const float* tv  = (const float*)d_in[5];

  float* ws = (float*)d_ws;
  float* partial = ws + 544;

  prep_kernel<<<1, 64, 0, stream>>>(hre, him, th, tv, ws);
  fused_kernel<<<NBLK, NTHR, 0, stream>>>(sre, sim, ws, partial);
  reduce_kernel<<<1, 256, 0, stream>>>(partial, (float*)d_out);
}

// Round 2
// 159.193 us; speedup vs baseline: 1.2393x; 1.2005x over previous
//
#include <hip/hip_runtime.h>
#include <math.h>

// Problem constants: 20 qubits, B=16 batch, RX chain on qubit 0,
// 2-qubit Hamiltonian evolution on qubits (2,5), observable = sum_q Z_q.
// State layout: (dim, B) row-major => flat idx = i*B + b; qubit q bit of i is at
// bit position (19 - q). So qubit 0 -> bit 19, qubit 2 -> bit 17, qubit 5 -> bit 14.
constexpr int NQ     = 20;
constexpr int DIM    = 1 << NQ;
constexpr int B      = 16;
constexpr int GROUPS = 1 << 17;   // DIM / 8 (octets over bits 19,17,14)
constexpr int NBLK   = 2048;
constexpr int NTHR   = 256;       // 2048*256 = 2^19 threads = GROUPS * 4 batch-quads

// ws layout (floats):
//   [0..15]    cos(0.5*sum theta) per batch
//   [16..31]   sin(0.5*sum theta) per batch
//   [32..543]  Ue per batch: b*32 + (i*4+j)*2 (+1 imag)

// ---- Prep: parallelized across 256 threads = 16 batches x 16 matrix elements.
// expm(-i t H) via fp64 scaling-squaring with LDS ping-pong for the 4x4 products.
__global__ __launch_bounds__(256) void prep_kernel(
    const float* __restrict__ hre, const float* __restrict__ him,
    const float* __restrict__ theta, const float* __restrict__ tv,
    float* __restrict__ ws, float* __restrict__ out) {
  __shared__ double Mre[16][16], Mim[16][16];
  __shared__ double Are[16][16], Aim[16][16];   // ping
  __shared__ double Bre[16][16], Bim[16][16];   // pong
  __shared__ double nrm[16][4];
  __shared__ int    scl[16];
  __shared__ int    scmax_s;

  int t = threadIdx.x;
  int b = t >> 4, e = t & 15, i = e >> 2, j = e & 3;

  if (t < 16) out[t] = 0.f;       // zero the global accumulators each replay
  if (t == 0) scmax_s = 0;

  // RX coeffs: all RX on the same qubit commute => product = RX(sum theta).
  if (e == 0) {
    double th = 0.0;
    for (int k = 0; k < 8; k++) th += (double)theta[k * B + b];
    th *= 0.5;
    ws[b]     = (float)cos(th);
    ws[B + b] = (float)sin(th);
  }

  // H = 0.5*(A + A^H);  M = -i * t * H  =>  Mre = t*Him, Mim = -t*Hre
  {
    double tt  = (double)tv[b];
    double are = hre[(i*4+j)*B + b], aim = him[(i*4+j)*B + b];
    double cre = hre[(j*4+i)*B + b], cim = him[(j*4+i)*B + b];
    double Hre = 0.5*(are + cre), Him = 0.5*(aim - cim);
    Mre[b][e] = tt * Him;
    Mim[b][e] = -tt * Hre;
  }
  __syncthreads();

  // inf-norm upper bound: row sums, then max; per-batch scaling exponent
  if (j == 0) {
    double r = 0.0;
    for (int m = 0; m < 4; m++) r += fabs(Mre[b][i*4+m]) + fabs(Mim[b][i*4+m]);
    nrm[b][i] = r;
  }
  __syncthreads();
  if (e == 0) {
    double ninf = fmax(fmax(nrm[b][0], nrm[b][1]), fmax(nrm[b][2], nrm[b][3]));
    int sc = 0;
    while (ninf > 0.25 && sc < 40) { ninf *= 0.5; sc++; }
    scl[b] = sc;
    atomicMax(&scmax_s, sc);
  }
  __syncthreads();
  int sc = scl[b];
  int scmax = scmax_s;
  {
    double scale = ldexp(1.0, -sc);
    Mre[b][e] *= scale; Mim[b][e] *= scale;
  }
  // T = I
  Are[b][e] = (i == j) ? 1.0 : 0.0;
  Aim[b][e] = 0.0;
  __syncthreads();

  double (*Tr)[16] = Are; double (*Ti)[16] = Aim;
  double (*Pr)[16] = Bre; double (*Pi)[16] = Bim;

  // Taylor via Horner: for k=13..1: T = I + M*T/k   (each thread owns one element)
  for (int k = 13; k >= 1; k--) {
    double rr = 0.0, ii = 0.0;
    for (int m = 0; m < 4; m++) {
      double mr = Mre[b][i*4+m], mi = Mim[b][i*4+m];
      double xr = Tr[b][m*4+j],  xi = Ti[b][m*4+j];
      rr += mr*xr - mi*xi;
      ii += mr*xi + mi*xr;
    }
    double inv = 1.0 / (double)k;
    Pr[b][e] = rr*inv + ((i == j) ? 1.0 : 0.0);
    Pi[b][e] = ii*inv;
    { double (*s)[16] = Tr; Tr = Pr; Pr = s; s = Ti; Ti = Pi; Pi = s; }
    __syncthreads();
  }
  // Squaring (uniform scmax iterations; batches with q >= sc just copy forward)
  for (int q = 0; q < scmax; q++) {
    double rr, ii;
    if (q < sc) {
      rr = 0.0; ii = 0.0;
      for (int m = 0; m < 4; m++) {
        double xr = Tr[b][i*4+m], xi = Ti[b][i*4+m];
        double yr = Tr[b][m*4+j], yi = Ti[b][m*4+j];
        rr += xr*yr - xi*yi;
        ii += xr*yi + xi*yr;
      }
    } else { rr = Tr[b][e]; ii = Ti[b][e]; }
    Pr[b][e] = rr; Pi[b][e] = ii;
    { double (*s)[16] = Tr; Tr = Pr; Pr = s; s = Ti; Ti = Pi; Pi = s; }
    __syncthreads();
  }

  float* ue = ws + 2*B + b*32;
  ue[e*2]     = (float)Tr[b][e];
  ue[e*2 + 1] = (float)Ti[b][e];
}

// RX(theta_sum) on qubit 0, applied per float4 component (component = batch within quad).
#define RXPAIR(j, f) { \
  float xr = R[j].f, xi = I[j].f, yr = R[(j)+4].f, yi = I[(j)+4].f; \
  R[j].f     = fmaf(c4.f, xr,  s4.f * yi); \
  I[j].f     = fmaf(c4.f, xi, -s4.f * yr); \
  R[(j)+4].f = fmaf(s4.f, xi,  c4.f * yr); \
  I[(j)+4].f = fmaf(c4.f, yi, -s4.f * xr); \
}

// Ue on (qubit2, qubit5) + weight-folded |amp|^2 accumulation for one batch (bi-th
// component f of the float4s). U rows read from LDS (broadcast, conflict-free pad).
#define UE_BI(f, bi, accv) \
  float accv = 0.f; \
  { \
    const float* ub = &u_lds[(b0 + (bi)) * 36]; \
    _Pragma("unroll") \
    for (int k = 0; k < 4; k++) { \
      float4 u0 = *(const float4*)(ub + 8*k);       /* ur0,ui0,ur1,ui1 */ \
      float4 u1 = *(const float4*)(ub + 8*k + 4);   /* ur2,ui2,ur3,ui3 */ \
      float rr0 = fmaf(u0.x, R[0].f, -u0.y * I[0].f); \
      rr0 = fmaf(u0.z, R[1].f, rr0); rr0 = fmaf(-u0.w, I[1].f, rr0); \
      rr0 = fmaf(u1.x, R[2].f, rr0); rr0 = fmaf(-u1.y, I[2].f, rr0); \
      rr0 = fmaf(u1.z, R[3].f, rr0); rr0 = fmaf(-u1.w, I[3].f, rr0); \
      float ii0 = fmaf(u0.x, I[0].f, u0.y * R[0].f); \
      ii0 = fmaf(u0.z, I[1].f, ii0); ii0 = fmaf(u0.w, R[1].f, ii0); \
      ii0 = fmaf(u1.x, I[2].f, ii0); ii0 = fmaf(u1.y, R[2].f, ii0); \
      ii0 = fmaf(u1.z, I[3].f, ii0); ii0 = fmaf(u1.w, R[3].f, ii0); \
      float rr1 = fmaf(u0.x, R[4].f, -u0.y * I[4].f); \
      rr1 = fmaf(u0.z, R[5].f, rr1); rr1 = fmaf(-u0.w, I[5].f, rr1); \
      rr1 = fmaf(u1.x, R[6].f, rr1); rr1 = fmaf(-u1.y, I[6].f, rr1); \
      rr1 = fmaf(u1.z, R[7].f, rr1); rr1 = fmaf(-u1.w, I[7].f, rr1); \
      float ii1 = fmaf(u0.x, I[4].f, u0.y * R[4].f); \
      ii1 = fmaf(u0.z, I[5].f, ii1); ii1 = fmaf(u0.w, R[5].f, ii1); \
      ii1 = fmaf(u1.x, I[6].f, ii1); ii1 = fmaf(u1.y, R[6].f, ii1); \
      ii1 = fmaf(u1.z, I[7].f, ii1); ii1 = fmaf(u1.w, R[7].f, ii1); \
      int sb = (k & 1) + (k >> 1); \
      float w0 = wb + (float)(3 - 2*sb);            /* h=0 weight */ \
      accv = fmaf(fmaf(rr0, rr0, ii0*ii0), w0,       accv); \
      accv = fmaf(fmaf(rr1, rr1, ii1*ii1), w0 - 2.f, accv); \
    } \
  }

// ---- Fused gate-apply + expectation. One group x 4 batches per thread; float4 loads.
// __launch_bounds__(256, 3): budget ~170 VGPRs so all 16 state float4s stay live
// (at (512)-default the compiler capped at 52 VGPRs and split/rematerialized loads).
__global__ __launch_bounds__(NTHR, 3) void fused_kernel(
    const float* __restrict__ sre, const float* __restrict__ sim,
    const float* __restrict__ ws, float* __restrict__ out) {
  __shared__ float u_lds[16 * 36];   // padded stride 36: 16B-aligned rows, conflict-free
  __shared__ float cs_lds[32];
  __shared__ float red[16];

  int t = threadIdx.x;
  {
    int bq = t & 15, e2 = t >> 4;    // 16 threads per batch row, 16 rows: t<256 covers 16x16
    u_lds[bq * 36 + e2 * 2]     = ws[2 * B + bq * 32 + e2 * 2];
    u_lds[bq * 36 + e2 * 2 + 1] = ws[2 * B + bq * 32 + e2 * 2 + 1];
  }
  if (t < 32) cs_lds[t] = ws[t];
  if (t < 16) red[t] = 0.f;
  __syncthreads();

  int tid = blockIdx.x * NTHR + t;
  int g   = tid >> 2;                  // 2^17 groups, exact cover
  int b0  = (tid & 3) << 2;            // batch quad base: 0,4,8,12
  // expand 17-bit group id into 20-bit base with bits 14,17,19 zero
  int base = (g & 0x3FFF) | ((g & 0xC000) << 1) | ((g & 0x10000) << 2);
  const float* pr = sre + base * B + b0;
  const float* pi = sim + base * B + b0;

  float4 R[8], I[8];
  #pragma unroll
  for (int j = 0; j < 8; j++) {
    int off = (((((j >> 2) & 1) << 19) | (((j >> 1) & 1) << 17) | ((j & 1) << 14))) * B;
    R[j] = *(const float4*)(pr + off);
    I[j] = *(const float4*)(pi + off);
  }

  float4 c4 = *(const float4*)&cs_lds[b0];
  float4 s4 = *(const float4*)&cs_lds[16 + b0];

  // RX on qubit 0 (bit j>>2): pairs (j, j+4); -i*s*(x) = s*xi - i*s*xr
  #pragma unroll
  for (int j = 0; j < 4; j++) {
    RXPAIR(j, x) RXPAIR(j, y) RXPAIR(j, z) RXPAIR(j, w)
  }

  int pc = __popc(base);
  float wb = (float)(17 - 2 * pc);

  UE_BI(x, 0, acc0)
  UE_BI(y, 1, acc1)
  UE_BI(z, 2, acc2)
  UE_BI(w, 3, acc3)

  // lanes with equal (t&3) share the batch quad => butterfly over lane bits 2..5
  #pragma unroll
  for (int m = 4; m <= 32; m <<= 1) {
    acc0 += __shfl_xor(acc0, m, 64);
    acc1 += __shfl_xor(acc1, m, 64);
    acc2 += __shfl_xor(acc2, m, 64);
    acc3 += __shfl_xor(acc3, m, 64);
  }

  if ((t & 63) < 4) {
    int bb = (t & 3) << 2;
    atomicAdd(&red[bb + 0], acc0);
    atomicAdd(&red[bb + 1], acc1);
    atomicAdd(&red[bb + 2], acc2);
    atomicAdd(&red[bb + 3], acc3);
  }
  __syncthreads();
  // one global atomic per (block, batch); blocks retire staggered => contention hidden
  if (t < 16) atomicAdd(&out[t], red[t]);
}

extern "C" void kernel_launch(void* const* d_in, const int* in_sizes, int n_in,
                              void* d_out, int out_size, void* d_ws, size_t ws_size,
                              hipStream_t stream) {
  const float* sre = (const float*)d_in[0];
  const float* sim = (const float*)d_in[1];
  const float* hre = (const float*)d_in[2];
  const float* him = (const float*)d_in[3];
  const float* th  = (const float*)d_in[4];
  const float* tv  = (const float*)d_in[5];

  float* ws = (float*)d_ws;
  float* out = (float*)d_out;

  prep_kernel<<<1, 256, 0, stream>>>(hre, him, th, tv, ws, out);
  fused_kernel<<<NBLK, NTHR, 0, stream>>>(sre, sim, ws, out);
}